// Round 7
// baseline (262.415 us; speedup 1.0000x reference)
//
#include <hip/hip_runtime.h>
#include <cstdint>
#include <cstddef>

typedef _Float16 f16;
typedef __attribute__((ext_vector_type(4))) _Float16 f16x4;
typedef __attribute__((ext_vector_type(8))) _Float16 f16x8;
typedef __attribute__((ext_vector_type(4))) float f32x4;

static constexpr int BB = 4;
static constexpr int SS = 2048;
static constexpr int EE = 1024;

static constexpr int BM = 128, BN = 128;   // K handled as 2x32 buffers per barrier

// async global->LDS, 16B per lane. LDS dest must be wave-uniform base + lane*16.
__device__ __forceinline__ void gload_lds16(const f16* g, f16* l) {
  __builtin_amdgcn_global_load_lds(
      (const __attribute__((address_space(1))) void*)g,
      (__attribute__((address_space(3))) void*)l, 16, 0, 0);
}

struct Frag {
  int lane, wave, wy, wx, l16, quad, quadx;
  __device__ Frag() {
    const int tid = threadIdx.x;
    lane = tid & 63; wave = tid >> 6;
    wy = wave >> 1; wx = wave & 1;
    l16 = lane & 15; quad = lane >> 4;
    quadx = quad ^ ((l16 >> 2) & 3);   // XOR-swizzled chunk select
  }
};

// Staging swizzle: LDS chunk c holds global chunk (row=c>>2, kc=(c&3)^((c>>4)&3)).
// 128x32 f16 tile = 512 chunks of 16B; 2 chunks/thread.
struct Stager {
  const f16* g[2];
  int l[2];
  __device__ void init(const f16* base, int ld, const Frag& fr) {
#pragma unroll
    for (int i = 0; i < 2; ++i) {
      const int c = fr.wave * 128 + i * 64 + fr.lane;
      const int row = c >> 2;
      const int kcs = (c & 3) ^ ((c >> 4) & 3);
      g[i] = base + (size_t)row * ld + kcs * 8;
      l[i] = c * 8;
    }
  }
  __device__ __forceinline__ void stage(int ko, f16* lds) const {
    gload_lds16(g[0] + ko, lds + l[0]);
    gload_lds16(g[1] + ko, lds + l[1]);
  }
};

// One 16-MFMA round from a staged 128x32 buffer pair
__device__ __forceinline__ void mfma_round(
    const f16* __restrict__ Ash, const f16* __restrict__ Bsh,
    f32x4 acc[4][4], const Frag& fr)
{
  f16x8 af[4], bf[4];
#pragma unroll
  for (int mi = 0; mi < 4; ++mi)
    af[mi] = *(const f16x8*)(Ash + (fr.wy * 64 + mi * 16 + fr.l16) * 32 + fr.quadx * 8);
#pragma unroll
  for (int ni = 0; ni < 4; ++ni)
    bf[ni] = *(const f16x8*)(Bsh + (fr.wx * 64 + ni * 16 + fr.l16) * 32 + fr.quadx * 8);
#pragma unroll
  for (int mi = 0; mi < 4; ++mi)
#pragma unroll
    for (int ni = 0; ni < 4; ++ni)
      acc[mi][ni] = __builtin_amdgcn_mfma_f32_16x16x32_f16(af[mi], bf[ni], acc[mi][ni], 0, 0, 0);
}

// C[m,n] = sum_k A[m,k]*Bt[n,k]; 2x(128x32) staged per barrier -> 32 MFMA/barrier
__device__ __forceinline__ void gemm_core(
    const f16* __restrict__ A, const f16* __restrict__ Bt,
    int lda, int ldb, int kOuter,
    f16* __restrict__ Ash, f16* __restrict__ Bsh,   // each [2][128*32]
    f32x4 acc[4][4], const Frag& fr)
{
  Stager sa, sb;
  sa.init(A, lda, fr);
  sb.init(Bt, ldb, fr);
  for (int kt = 0; kt < kOuter; ++kt) {
    const int ko = kt * 64;
    sa.stage(ko, Ash);       sa.stage(ko + 32, Ash + 128 * 32);
    sb.stage(ko, Bsh);       sb.stage(ko + 32, Bsh + 128 * 32);
    __syncthreads();
    mfma_round(Ash, Bsh, acc, fr);
    mfma_round(Ash + 128 * 32, Bsh + 128 * 32, acc, fr);
    __syncthreads();
  }
}

// ---------------- cast fp32 -> f16 ----------------
__global__ __launch_bounds__(256) void cast_kernel(
    const float* __restrict__ in, f16* __restrict__ out, int n4)
{
  const int i = blockIdx.x * 256 + threadIdx.x;
  if (i < n4) {
    const float4 f = ((const float4*)in)[i];
    f16x4 h;
    h.x = (f16)f.x; h.y = (f16)f.y; h.z = (f16)f.z; h.w = (f16)f.w;
    ((f16x4*)out)[i] = h;
  }
}

__global__ __launch_bounds__(256) void cast_w_kernel(
    const float* __restrict__ w0, const float* __restrict__ w1, const float* __restrict__ w2,
    f16* __restrict__ o0, f16* __restrict__ o1, f16* __restrict__ o2, int n4)
{
  const int z = blockIdx.y;
  const float* in = (z == 0) ? w0 : (z == 1) ? w1 : w2;
  f16* out = (z == 0) ? o0 : (z == 1) ? o1 : o2;
  const int i = blockIdx.x * 256 + threadIdx.x;
  if (i < n4) {
    const float4 f = ((const float4*)in)[i];
    f16x4 h;
    h.x = (f16)f.x; h.y = (f16)f.y; h.z = (f16)f.z; h.w = (f16)f.w;
    ((f16x4*)out)[i] = h;
  }
}

// ---------------- fused QK: A + 2 W staged as 2x32 buffers; 64 MFMA/barrier ----------------
// acc 2x64 f32 -> ~2 waves/SIMD (vs z=3's ~1.5). LDS 48KB/block, 2 blocks/CU.
__global__ __launch_bounds__(256, 2) void qk_fused_kernel(
    const f16* __restrict__ X,
    const f16* __restrict__ W0, const f16* __restrict__ W1,
    const float* __restrict__ b0, const float* __restrict__ b1,
    f16* __restrict__ O0, f16* __restrict__ O1)
{
  __shared__ __align__(16) f16 Ash[2][BM * 32];
  __shared__ __align__(16) f16 Bsh[2][2][BN * 32];
  const int row0 = blockIdx.x * BM, col0 = blockIdx.y * BN;
  Frag fr;

  Stager sa, sw[2];
  sa.init(X + (size_t)row0 * EE, EE, fr);
  sw[0].init(W0 + (size_t)col0 * EE, EE, fr);
  sw[1].init(W1 + (size_t)col0 * EE, EE, fr);

  f32x4 acc[2][4][4] = {};

  for (int kt = 0; kt < EE / 64; ++kt) {
    const int ko = kt * 64;
    sa.stage(ko, Ash[0]);  sa.stage(ko + 32, Ash[1]);
#pragma unroll
    for (int z = 0; z < 2; ++z) {
      sw[z].stage(ko, Bsh[z][0]);  sw[z].stage(ko + 32, Bsh[z][1]);
    }
    __syncthreads();
#pragma unroll
    for (int h = 0; h < 2; ++h) {
      f16x8 af[4];
#pragma unroll
      for (int mi = 0; mi < 4; ++mi)
        af[mi] = *(const f16x8*)(Ash[h] + (fr.wy * 64 + mi * 16 + fr.l16) * 32 + fr.quadx * 8);
#pragma unroll
      for (int z = 0; z < 2; ++z) {
        f16x8 bf[4];
#pragma unroll
        for (int ni = 0; ni < 4; ++ni)
          bf[ni] = *(const f16x8*)(Bsh[z][h] + (fr.wx * 64 + ni * 16 + fr.l16) * 32 + fr.quadx * 8);
#pragma unroll
        for (int mi = 0; mi < 4; ++mi)
#pragma unroll
          for (int ni = 0; ni < 4; ++ni)
            acc[z][mi][ni] = __builtin_amdgcn_mfma_f32_16x16x32_f16(af[mi], bf[ni], acc[z][mi][ni], 0, 0, 0);
      }
    }
    __syncthreads();
  }

#pragma unroll
  for (int z = 0; z < 2; ++z) {
    const float* bias = (z == 0) ? b0 : b1;
    f16* out = (z == 0) ? O0 : O1;
#pragma unroll
    for (int ni = 0; ni < 4; ++ni) {
      const int c = col0 + fr.wx * 64 + ni * 16 + fr.l16;
      const float bv = bias[c];
#pragma unroll
      for (int mi = 0; mi < 4; ++mi) {
        const int r = row0 + fr.wy * 64 + mi * 16 + fr.quad * 4;
#pragma unroll
        for (int i = 0; i < 4; ++i)
          out[(size_t)(r + i) * EE + c] = (f16)(acc[z][mi][ni][i] + bv);
      }
    }
  }
}

// ---------------- V^T projection: Vt[e][s] = sum_h Wv[e,h] X[s,h] + bv[e] ----------------
// Same BT-GEMM with A=Wv (M=e), Bt=X (N=s-global). Writes Vt directly -> no transpose pass.
// Bias varies along M (rows), applied per output row in the epilogue.
__global__ __launch_bounds__(256, 2) void vt_gemm_kernel(
    const f16* __restrict__ Wv, const f16* __restrict__ X,
    const float* __restrict__ bv, f16* __restrict__ Vt)
{
  __shared__ __align__(16) f16 Ash[2][BM * 32];
  __shared__ __align__(16) f16 Bsh[2][BN * 32];
  const int row0 = blockIdx.x * BM;          // e
  const int sg0 = blockIdx.y * BN;           // global s in [0, BB*SS)
  const int b = sg0 / SS, s0 = sg0 % SS;     // 128-tile always within one batch
  Frag fr;
  f32x4 acc[4][4] = {};
  gemm_core(Wv + (size_t)row0 * EE, X + (size_t)sg0 * EE, EE, EE, EE / 64,
            Ash[0], Bsh[0], acc, fr);
  f16* out = Vt + (size_t)b * EE * SS;
#pragma unroll
  for (int ni = 0; ni < 4; ++ni) {
    const int c = s0 + fr.wx * 64 + ni * 16 + fr.l16;
#pragma unroll
    for (int mi = 0; mi < 4; ++mi) {
      const int r = row0 + fr.wy * 64 + mi * 16 + fr.quad * 4;
#pragma unroll
      for (int i = 0; i < 4; ++i)
        out[(size_t)(r + i) * SS + c] = (f16)(acc[mi][ni][i] + bv[r + i]);
    }
  }
}

// ---------------- scores: Sc[q,k] = (Q[q,:] . K[k,:]) / 32, lower-tri tiles only ----------------
__global__ __launch_bounds__(256) void scores_kernel(
    const f16* __restrict__ Q, const f16* __restrict__ Kh, f16* __restrict__ Sc)
{
  __shared__ __align__(16) f16 Ash[2][BM * 32];
  __shared__ __align__(16) f16 Bsh[2][BN * 32];
  const int t = blockIdx.x, b = blockIdx.z;
  int qt = 0;
  while ((qt + 1) * (qt + 2) / 2 <= t) ++qt;
  const int kt = t - qt * (qt + 1) / 2;
  const f16* A  = Q  + (size_t)b * SS * EE + (size_t)qt * BM * EE;
  const f16* Bp = Kh + (size_t)b * SS * EE + (size_t)kt * BN * EE;
  f16* out = Sc + (size_t)b * SS * SS;
  Frag fr;
  f32x4 acc[4][4] = {};
  gemm_core(A, Bp, EE, EE, EE / 64, Ash[0], Bsh[0], acc, fr);
  const float scale = 0.03125f;   // 1/sqrt(1024)
#pragma unroll
  for (int ni = 0; ni < 4; ++ni) {
    const int c = kt * BN + fr.wx * 64 + ni * 16 + fr.l16;
#pragma unroll
    for (int mi = 0; mi < 4; ++mi) {
      const int r = qt * BM + fr.wy * 64 + mi * 16 + fr.quad * 4;
#pragma unroll
      for (int i = 0; i < 4; ++i)
        out[(size_t)(r + i) * SS + c] = (f16)(acc[mi][ni][i] * scale);
    }
  }
}

// ---------------- in-place causal softmax over row q (vectorized f16x8) ----------------
__global__ __launch_bounds__(256) void softmax_kernel(f16* __restrict__ Sc)
{
  const int q = blockIdx.x, b = blockIdx.y;
  f16* row = Sc + (size_t)b * SS * SS + (size_t)q * SS;
  const int n = q + 1;
  const int kend = ((q >> 7) + 1) << 7;   // PV reads K up to this 128-boundary
  const int tid = threadIdx.x;
  const int i0 = tid * 8;

  float v[8];
  if (i0 + 8 <= n) {
    const f16x8 h = *(const f16x8*)(row + i0);
#pragma unroll
    for (int j = 0; j < 8; ++j) v[j] = (float)h[j];
  } else {
#pragma unroll
    for (int j = 0; j < 8; ++j) {
      const int idx = i0 + j;
      v[j] = (idx < n) ? (float)row[idx] : -1e30f;
    }
  }

  float m = v[0];
#pragma unroll
  for (int j = 1; j < 8; ++j) m = fmaxf(m, v[j]);
  __shared__ float red[4];
#pragma unroll
  for (int off = 32; off > 0; off >>= 1) m = fmaxf(m, __shfl_down(m, off));
  if ((tid & 63) == 0) red[tid >> 6] = m;
  __syncthreads();
  m = fmaxf(fmaxf(red[0], red[1]), fmaxf(red[2], red[3]));

  float sum = 0.f;
#pragma unroll
  for (int j = 0; j < 8; ++j) {
    v[j] = (i0 + j < n) ? __expf(v[j] - m) : 0.f;
    sum += v[j];
  }
#pragma unroll
  for (int off = 32; off > 0; off >>= 1) sum += __shfl_down(sum, off);
  __syncthreads();
  if ((tid & 63) == 0) red[tid >> 6] = sum;
  __syncthreads();
  sum = red[0] + red[1] + red[2] + red[3];
  const float inv = 1.f / sum;

  if (i0 < kend) {
    f16x8 h;
#pragma unroll
    for (int j = 0; j < 8; ++j) h[j] = (f16)(v[j] * inv);   // v==0 beyond n
    *(f16x8*)(row + i0) = h;
  }
}

// ---------------- PV: Y[q,e] = sum_{k<=q} P[q,k] * Vt[e,k], fp32 out ----------------
__global__ __launch_bounds__(256) void pv_kernel(
    const f16* __restrict__ P, const f16* __restrict__ Vt, float* __restrict__ Y)
{
  __shared__ __align__(16) f16 Ash[2][BM * 32];
  __shared__ __align__(16) f16 Bsh[2][BN * 32];
  const int qt = (gridDim.x - 1) - blockIdx.x, et = blockIdx.y, b = blockIdx.z;
  const f16* A  = P  + (size_t)b * SS * SS + (size_t)qt * BM * SS;
  const f16* Bp = Vt + (size_t)b * EE * SS + (size_t)et * BN * SS;
  float* out = Y + (size_t)b * SS * EE;
  Frag fr;
  f32x4 acc[4][4] = {};
  gemm_core(A, Bp, SS, SS, (qt + 1) * 2, Ash[0], Bsh[0], acc, fr);
#pragma unroll
  for (int ni = 0; ni < 4; ++ni) {
    const int c = et * BN + fr.wx * 64 + ni * 16 + fr.l16;
#pragma unroll
    for (int mi = 0; mi < 4; ++mi) {
      const int r = qt * BM + fr.wy * 64 + mi * 16 + fr.quad * 4;
#pragma unroll
      for (int i = 0; i < 4; ++i)
        out[(size_t)(r + i) * EE + c] = acc[mi][ni][i];
    }
  }
}

extern "C" void kernel_launch(void* const* d_in, const int* in_sizes, int n_in,
                              void* d_out, int out_size, void* d_ws, size_t ws_size,
                              hipStream_t stream)
{
  const float* xs  = (const float*)d_in[0];
  const float* WQw = (const float*)d_in[1];
  const float* WQb = (const float*)d_in[2];
  const float* WKw = (const float*)d_in[3];
  const float* WKb = (const float*)d_in[4];
  const float* WVw = (const float*)d_in[5];
  const float* WVb = (const float*)d_in[6];

  const size_t ME = (size_t)BB * SS * EE;   // 8M tokens*dim
  const size_t WE = (size_t)EE * EE;        // 1M weight elems

  f16* Xh = (f16*)d_ws;
  f16* Wq = Xh + ME;
  f16* Wk = Wq + WE;
  f16* Wv = Wk + WE;
  f16* Qh = Wv + WE;
  f16* Kh = Qh + ME;
  f16* Vt = Kh + ME;
  f16* Sc = Vt + ME;   // BB*SS*SS f16 = 32 MiB

  cast_kernel<<<dim3((unsigned)(ME / 4 / 256)), 256, 0, stream>>>(xs, Xh, (int)(ME / 4));
  cast_w_kernel<<<dim3((unsigned)(WE / 4 / 256), 3), 256, 0, stream>>>(
      WQw, WKw, WVw, Wq, Wk, Wv, (int)(WE / 4));

  qk_fused_kernel<<<dim3((BB * SS) / BM, EE / BN), 256, 0, stream>>>(
      Xh, Wq, Wk, WQb, WKb, Qh, Kh);
  vt_gemm_kernel<<<dim3(EE / BM, (BB * SS) / BN), 256, 0, stream>>>(
      Wv, Xh, WVb, Vt);
  const int nTri = (SS / BM) * (SS / BM + 1) / 2;   // 136
  scores_kernel<<<dim3(nTri, 1, BB), 256, 0, stream>>>(Qh, Kh, Sc);
  softmax_kernel<<<dim3(SS, BB), 256, 0, stream>>>(Sc);
  pv_kernel<<<dim3(SS / BM, EE / BN, BB), 256, 0, stream>>>(Sc, Vt, (float*)d_out);
}

// Round 8
// 259.444 us; speedup vs baseline: 1.0115x; 1.0115x over previous
//
#include <hip/hip_runtime.h>
#include <cstdint>
#include <cstddef>

typedef _Float16 f16;
typedef __attribute__((ext_vector_type(4))) _Float16 f16x4;
typedef __attribute__((ext_vector_type(8))) _Float16 f16x8;
typedef __attribute__((ext_vector_type(4))) float f32x4;

static constexpr int BB = 4;
static constexpr int SS = 2048;
static constexpr int EE = 1024;

static constexpr int BM = 128, BN = 128;   // K handled as 2x32 buffers per barrier

// async global->LDS, 16B per lane. LDS dest must be wave-uniform base + lane*16.
__device__ __forceinline__ void gload_lds16(const f16* g, f16* l) {
  __builtin_amdgcn_global_load_lds(
      (const __attribute__((address_space(1))) void*)g,
      (__attribute__((address_space(3))) void*)l, 16, 0, 0);
}

struct Frag {
  int lane, wave, wy, wx, l16, quad, quadx;
  __device__ Frag() {
    const int tid = threadIdx.x;
    lane = tid & 63; wave = tid >> 6;
    wy = wave >> 1; wx = wave & 1;
    l16 = lane & 15; quad = lane >> 4;
    quadx = quad ^ ((l16 >> 2) & 3);   // XOR-swizzled chunk select
  }
};

// Staging swizzle: LDS chunk c holds global chunk (row=c>>2, kc=(c&3)^((c>>4)&3)).
// 128x32 f16 tile = 512 chunks of 16B; 2 chunks/thread.
struct Stager {
  const f16* g[2];
  int l[2];
  __device__ void init(const f16* base, int ld, const Frag& fr) {
#pragma unroll
    for (int i = 0; i < 2; ++i) {
      const int c = fr.wave * 128 + i * 64 + fr.lane;
      const int row = c >> 2;
      const int kcs = (c & 3) ^ ((c >> 4) & 3);
      g[i] = base + (size_t)row * ld + kcs * 8;
      l[i] = c * 8;
    }
  }
  __device__ __forceinline__ void stage(int ko, f16* lds) const {
    gload_lds16(g[0] + ko, lds + l[0]);
    gload_lds16(g[1] + ko, lds + l[1]);
  }
};

// One 16-MFMA round from a staged 128x32 buffer pair
__device__ __forceinline__ void mfma_round(
    const f16* __restrict__ Ash, const f16* __restrict__ Bsh,
    f32x4 acc[4][4], const Frag& fr)
{
  f16x8 af[4], bf[4];
#pragma unroll
  for (int mi = 0; mi < 4; ++mi)
    af[mi] = *(const f16x8*)(Ash + (fr.wy * 64 + mi * 16 + fr.l16) * 32 + fr.quadx * 8);
#pragma unroll
  for (int ni = 0; ni < 4; ++ni)
    bf[ni] = *(const f16x8*)(Bsh + (fr.wx * 64 + ni * 16 + fr.l16) * 32 + fr.quadx * 8);
#pragma unroll
  for (int mi = 0; mi < 4; ++mi)
#pragma unroll
    for (int ni = 0; ni < 4; ++ni)
      acc[mi][ni] = __builtin_amdgcn_mfma_f32_16x16x32_f16(af[mi], bf[ni], acc[mi][ni], 0, 0, 0);
}

// C[m,n] = sum_k A[m,k]*Bt[n,k]; 2x(128x32) staged per barrier -> 32 MFMA/barrier
__device__ __forceinline__ void gemm_core(
    const f16* __restrict__ A, const f16* __restrict__ Bt,
    int lda, int ldb, int kOuter,
    f16* __restrict__ Ash, f16* __restrict__ Bsh,   // each [2][128*32]
    f32x4 acc[4][4], const Frag& fr)
{
  Stager sa, sb;
  sa.init(A, lda, fr);
  sb.init(Bt, ldb, fr);
  for (int kt = 0; kt < kOuter; ++kt) {
    const int ko = kt * 64;
    sa.stage(ko, Ash);       sa.stage(ko + 32, Ash + 128 * 32);
    sb.stage(ko, Bsh);       sb.stage(ko + 32, Bsh + 128 * 32);
    __syncthreads();
    mfma_round(Ash, Bsh, acc, fr);
    mfma_round(Ash + 128 * 32, Bsh + 128 * 32, acc, fr);
    __syncthreads();
  }
}

// ---------------- cast fp32 -> f16 ----------------
__global__ __launch_bounds__(256) void cast_kernel(
    const float* __restrict__ in, f16* __restrict__ out, int n4)
{
  const int i = blockIdx.x * 256 + threadIdx.x;
  if (i < n4) {
    const float4 f = ((const float4*)in)[i];
    f16x4 h;
    h.x = (f16)f.x; h.y = (f16)f.y; h.z = (f16)f.z; h.w = (f16)f.w;
    ((f16x4*)out)[i] = h;
  }
}

__global__ __launch_bounds__(256) void cast_w_kernel(
    const float* __restrict__ w0, const float* __restrict__ w1, const float* __restrict__ w2,
    f16* __restrict__ o0, f16* __restrict__ o1, f16* __restrict__ o2, int n4)
{
  const int z = blockIdx.y;
  const float* in = (z == 0) ? w0 : (z == 1) ? w1 : w2;
  f16* out = (z == 0) ? o0 : (z == 1) ? o1 : o2;
  const int i = blockIdx.x * 256 + threadIdx.x;
  if (i < n4) {
    const float4 f = ((const float4*)in)[i];
    f16x4 h;
    h.x = (f16)f.x; h.y = (f16)f.y; h.z = (f16)f.z; h.w = (f16)f.w;
    ((f16x4*)out)[i] = h;
  }
}

// ---------------- fused QK: A + 2 W staged as 2x32 buffers; 64 MFMA/barrier ----------------
__global__ __launch_bounds__(256, 2) void qk_fused_kernel(
    const f16* __restrict__ X,
    const f16* __restrict__ W0, const f16* __restrict__ W1,
    const float* __restrict__ b0, const float* __restrict__ b1,
    f16* __restrict__ O0, f16* __restrict__ O1)
{
  __shared__ __align__(16) f16 Ash[2][BM * 32];
  __shared__ __align__(16) f16 Bsh[2][2][BN * 32];
  const int row0 = blockIdx.x * BM, col0 = blockIdx.y * BN;
  Frag fr;

  Stager sa, sw[2];
  sa.init(X + (size_t)row0 * EE, EE, fr);
  sw[0].init(W0 + (size_t)col0 * EE, EE, fr);
  sw[1].init(W1 + (size_t)col0 * EE, EE, fr);

  f32x4 acc[2][4][4] = {};

  for (int kt = 0; kt < EE / 64; ++kt) {
    const int ko = kt * 64;
    sa.stage(ko, Ash[0]);  sa.stage(ko + 32, Ash[1]);
#pragma unroll
    for (int z = 0; z < 2; ++z) {
      sw[z].stage(ko, Bsh[z][0]);  sw[z].stage(ko + 32, Bsh[z][1]);
    }
    __syncthreads();
#pragma unroll
    for (int h = 0; h < 2; ++h) {
      f16x8 af[4];
#pragma unroll
      for (int mi = 0; mi < 4; ++mi)
        af[mi] = *(const f16x8*)(Ash[h] + (fr.wy * 64 + mi * 16 + fr.l16) * 32 + fr.quadx * 8);
#pragma unroll
      for (int z = 0; z < 2; ++z) {
        f16x8 bf[4];
#pragma unroll
        for (int ni = 0; ni < 4; ++ni)
          bf[ni] = *(const f16x8*)(Bsh[z][h] + (fr.wx * 64 + ni * 16 + fr.l16) * 32 + fr.quadx * 8);
#pragma unroll
        for (int mi = 0; mi < 4; ++mi)
#pragma unroll
          for (int ni = 0; ni < 4; ++ni)
            acc[z][mi][ni] = __builtin_amdgcn_mfma_f32_16x16x32_f16(af[mi], bf[ni], acc[z][mi][ni], 0, 0, 0);
      }
    }
    __syncthreads();
  }

#pragma unroll
  for (int z = 0; z < 2; ++z) {
    const float* bias = (z == 0) ? b0 : b1;
    f16* out = (z == 0) ? O0 : O1;
#pragma unroll
    for (int ni = 0; ni < 4; ++ni) {
      const int c = col0 + fr.wx * 64 + ni * 16 + fr.l16;
      const float bv = bias[c];
#pragma unroll
      for (int mi = 0; mi < 4; ++mi) {
        const int r = row0 + fr.wy * 64 + mi * 16 + fr.quad * 4;
#pragma unroll
        for (int i = 0; i < 4; ++i)
          out[(size_t)(r + i) * EE + c] = (f16)(acc[z][mi][ni][i] + bv);
      }
    }
  }
}

// ---------------- V^T projection: Vt[e][s] = sum_h Wv[e,h] X[s,h] + bv[e] ----------------
__global__ __launch_bounds__(256, 2) void vt_gemm_kernel(
    const f16* __restrict__ Wv, const f16* __restrict__ X,
    const float* __restrict__ bv, f16* __restrict__ Vt)
{
  __shared__ __align__(16) f16 Ash[2][BM * 32];
  __shared__ __align__(16) f16 Bsh[2][BN * 32];
  const int row0 = blockIdx.x * BM;          // e
  const int sg0 = blockIdx.y * BN;           // global s in [0, BB*SS)
  const int b = sg0 / SS, s0 = sg0 % SS;     // 128-tile always within one batch
  Frag fr;
  f32x4 acc[4][4] = {};
  gemm_core(Wv + (size_t)row0 * EE, X + (size_t)sg0 * EE, EE, EE, EE / 64,
            Ash[0], Bsh[0], acc, fr);
  f16* out = Vt + (size_t)b * EE * SS;
#pragma unroll
  for (int ni = 0; ni < 4; ++ni) {
    const int c = s0 + fr.wx * 64 + ni * 16 + fr.l16;
#pragma unroll
    for (int mi = 0; mi < 4; ++mi) {
      const int r = row0 + fr.wy * 64 + mi * 16 + fr.quad * 4;
#pragma unroll
      for (int i = 0; i < 4; ++i)
        out[(size_t)(r + i) * SS + c] = (f16)(acc[mi][ni][i] + bv[r + i]);
    }
  }
}

// ---------------- scores: Sc[q,k] = (Q[q,:] . K[k,:]) / 32, lower-tri tiles only ----------------
__global__ __launch_bounds__(256) void scores_kernel(
    const f16* __restrict__ Q, const f16* __restrict__ Kh, f16* __restrict__ Sc)
{
  __shared__ __align__(16) f16 Ash[2][BM * 32];
  __shared__ __align__(16) f16 Bsh[2][BN * 32];
  const int t = blockIdx.x, b = blockIdx.z;
  int qt = 0;
  while ((qt + 1) * (qt + 2) / 2 <= t) ++qt;
  const int kt = t - qt * (qt + 1) / 2;
  const f16* A  = Q  + (size_t)b * SS * EE + (size_t)qt * BM * EE;
  const f16* Bp = Kh + (size_t)b * SS * EE + (size_t)kt * BN * EE;
  f16* out = Sc + (size_t)b * SS * SS;
  Frag fr;
  f32x4 acc[4][4] = {};
  gemm_core(A, Bp, EE, EE, EE / 64, Ash[0], Bsh[0], acc, fr);
  const float scale = 0.03125f;   // 1/sqrt(1024)
#pragma unroll
  for (int ni = 0; ni < 4; ++ni) {
    const int c = kt * BN + fr.wx * 64 + ni * 16 + fr.l16;
#pragma unroll
    for (int mi = 0; mi < 4; ++mi) {
      const int r = qt * BM + fr.wy * 64 + mi * 16 + fr.quad * 4;
#pragma unroll
      for (int i = 0; i < 4; ++i)
        out[(size_t)(r + i) * SS + c] = (f16)(acc[mi][ni][i] * scale);
    }
  }
}

// ---------------- in-place causal softmax over row q (vectorized f16x8) ----------------
__global__ __launch_bounds__(256) void softmax_kernel(f16* __restrict__ Sc)
{
  const int q = blockIdx.x, b = blockIdx.y;
  f16* row = Sc + (size_t)b * SS * SS + (size_t)q * SS;
  const int n = q + 1;
  const int kend = ((q >> 7) + 1) << 7;   // PV reads K up to this 128-boundary
  const int tid = threadIdx.x;
  const int i0 = tid * 8;

  float v[8];
  if (i0 + 8 <= n) {
    const f16x8 h = *(const f16x8*)(row + i0);
#pragma unroll
    for (int j = 0; j < 8; ++j) v[j] = (float)h[j];
  } else {
#pragma unroll
    for (int j = 0; j < 8; ++j) {
      const int idx = i0 + j;
      v[j] = (idx < n) ? (float)row[idx] : -1e30f;
    }
  }

  float m = v[0];
#pragma unroll
  for (int j = 1; j < 8; ++j) m = fmaxf(m, v[j]);
  __shared__ float red[4];
#pragma unroll
  for (int off = 32; off > 0; off >>= 1) m = fmaxf(m, __shfl_down(m, off));
  if ((tid & 63) == 0) red[tid >> 6] = m;
  __syncthreads();
  m = fmaxf(fmaxf(red[0], red[1]), fmaxf(red[2], red[3]));

  float sum = 0.f;
#pragma unroll
  for (int j = 0; j < 8; ++j) {
    v[j] = (i0 + j < n) ? __expf(v[j] - m) : 0.f;
    sum += v[j];
  }
#pragma unroll
  for (int off = 32; off > 0; off >>= 1) sum += __shfl_down(sum, off);
  __syncthreads();
  if ((tid & 63) == 0) red[tid >> 6] = sum;
  __syncthreads();
  sum = red[0] + red[1] + red[2] + red[3];
  const float inv = 1.f / sum;

  if (i0 < kend) {
    f16x8 h;
#pragma unroll
    for (int j = 0; j < 8; ++j) h[j] = (f16)(v[j] * inv);   // v==0 beyond n
    *(f16x8*)(row + i0) = h;
  }
}

// ---------------- PV: Y[q,e] = sum_{k<=q} P[q,k] * Vt[e,k], fp32 out ----------------
// Flat 512-block grid with complementary-pair remap: block t and t+256 map to
// qt=15-qh and qt=qh (same et,b) -> under round-robin block->CU placement each
// CU gets 17 K-tiles of work total, fixing the 16x per-CU imbalance (R7: 11% util).
__global__ __launch_bounds__(256) void pv_kernel(
    const f16* __restrict__ P, const f16* __restrict__ Vt, float* __restrict__ Y)
{
  __shared__ __align__(16) f16 Ash[2][BM * 32];
  __shared__ __align__(16) f16 Bsh[2][BN * 32];
  const int t = blockIdx.x;
  const int u = t & 255;
  const int qh = u & 7, et = (u >> 3) & 7, b = u >> 6;
  const int qt = (t < 256) ? (15 - qh) : qh;
  const f16* A  = P  + (size_t)b * SS * SS + (size_t)qt * BM * SS;
  const f16* Bp = Vt + (size_t)b * EE * SS + (size_t)et * BN * SS;
  float* out = Y + (size_t)b * SS * EE;
  Frag fr;
  f32x4 acc[4][4] = {};
  gemm_core(A, Bp, SS, SS, (qt + 1) * 2, Ash[0], Bsh[0], acc, fr);
#pragma unroll
  for (int ni = 0; ni < 4; ++ni) {
    const int c = et * BN + fr.wx * 64 + ni * 16 + fr.l16;
#pragma unroll
    for (int mi = 0; mi < 4; ++mi) {
      const int r = qt * BM + fr.wy * 64 + mi * 16 + fr.quad * 4;
#pragma unroll
      for (int i = 0; i < 4; ++i)
        out[(size_t)(r + i) * EE + c] = acc[mi][ni][i];
    }
  }
}

extern "C" void kernel_launch(void* const* d_in, const int* in_sizes, int n_in,
                              void* d_out, int out_size, void* d_ws, size_t ws_size,
                              hipStream_t stream)
{
  const float* xs  = (const float*)d_in[0];
  const float* WQw = (const float*)d_in[1];
  const float* WQb = (const float*)d_in[2];
  const float* WKw = (const float*)d_in[3];
  const float* WKb = (const float*)d_in[4];
  const float* WVw = (const float*)d_in[5];
  const float* WVb = (const float*)d_in[6];

  const size_t ME = (size_t)BB * SS * EE;   // 8M tokens*dim
  const size_t WE = (size_t)EE * EE;        // 1M weight elems

  f16* Xh = (f16*)d_ws;
  f16* Wq = Xh + ME;
  f16* Wk = Wq + WE;
  f16* Wv = Wk + WE;
  f16* Qh = Wv + WE;
  f16* Kh = Qh + ME;
  f16* Vt = Kh + ME;
  f16* Sc = Vt + ME;   // BB*SS*SS f16 = 32 MiB

  cast_kernel<<<dim3((unsigned)(ME / 4 / 256)), 256, 0, stream>>>(xs, Xh, (int)(ME / 4));
  cast_w_kernel<<<dim3((unsigned)(WE / 4 / 256), 3), 256, 0, stream>>>(
      WQw, WKw, WVw, Wq, Wk, Wv, (int)(WE / 4));

  qk_fused_kernel<<<dim3((BB * SS) / BM, EE / BN), 256, 0, stream>>>(
      Xh, Wq, Wk, WQb, WKb, Qh, Kh);
  vt_gemm_kernel<<<dim3(EE / BM, (BB * SS) / BN), 256, 0, stream>>>(
      Wv, Xh, WVb, Vt);
  const int nTri = (SS / BM) * (SS / BM + 1) / 2;   // 136
  scores_kernel<<<dim3(nTri, 1, BB), 256, 0, stream>>>(Qh, Kh, Sc);
  softmax_kernel<<<dim3(SS, BB), 256, 0, stream>>>(Sc);
  pv_kernel<<<dim3(512), 256, 0, stream>>>(Sc, Vt, (float*)d_out);
}

// Round 9
// 258.501 us; speedup vs baseline: 1.0151x; 1.0036x over previous
//
#include <hip/hip_runtime.h>
#include <cstdint>
#include <cstddef>

typedef _Float16 f16;
typedef __attribute__((ext_vector_type(4))) _Float16 f16x4;
typedef __attribute__((ext_vector_type(8))) _Float16 f16x8;
typedef __attribute__((ext_vector_type(4))) float f32x4;

static constexpr int BB = 4;
static constexpr int SS = 2048;
static constexpr int EE = 1024;

static constexpr int BM = 128, BN = 128;   // K handled as 2x32 buffers per barrier

// async global->LDS, 16B per lane. LDS dest must be wave-uniform base + lane*16.
__device__ __forceinline__ void gload_lds16(const f16* g, f16* l) {
  __builtin_amdgcn_global_load_lds(
      (const __attribute__((address_space(1))) void*)g,
      (__attribute__((address_space(3))) void*)l, 16, 0, 0);
}

struct Frag {
  int lane, wave, wy, wx, l16, quad, quadx;
  __device__ Frag() {
    const int tid = threadIdx.x;
    lane = tid & 63; wave = tid >> 6;
    wy = wave >> 1; wx = wave & 1;
    l16 = lane & 15; quad = lane >> 4;
    quadx = quad ^ ((l16 >> 2) & 3);   // XOR-swizzled chunk select
  }
};

// Staging swizzle: LDS chunk c holds global chunk (row=c>>2, kc=(c&3)^((c>>4)&3)).
// 128x32 f16 tile = 512 chunks of 16B; 2 chunks/thread.
struct Stager {
  const f16* g[2];
  int l[2];
  __device__ void init(const f16* base, int ld, const Frag& fr) {
#pragma unroll
    for (int i = 0; i < 2; ++i) {
      const int c = fr.wave * 128 + i * 64 + fr.lane;
      const int row = c >> 2;
      const int kcs = (c & 3) ^ ((c >> 4) & 3);
      g[i] = base + (size_t)row * ld + kcs * 8;
      l[i] = c * 8;
    }
  }
  __device__ __forceinline__ void stage(int ko, f16* lds) const {
    gload_lds16(g[0] + ko, lds + l[0]);
    gload_lds16(g[1] + ko, lds + l[1]);
  }
};

// One 16-MFMA round from a staged 128x32 buffer pair
__device__ __forceinline__ void mfma_round(
    const f16* __restrict__ Ash, const f16* __restrict__ Bsh,
    f32x4 acc[4][4], const Frag& fr)
{
  f16x8 af[4], bf[4];
#pragma unroll
  for (int mi = 0; mi < 4; ++mi)
    af[mi] = *(const f16x8*)(Ash + (fr.wy * 64 + mi * 16 + fr.l16) * 32 + fr.quadx * 8);
#pragma unroll
  for (int ni = 0; ni < 4; ++ni)
    bf[ni] = *(const f16x8*)(Bsh + (fr.wx * 64 + ni * 16 + fr.l16) * 32 + fr.quadx * 8);
#pragma unroll
  for (int mi = 0; mi < 4; ++mi)
#pragma unroll
    for (int ni = 0; ni < 4; ++ni)
      acc[mi][ni] = __builtin_amdgcn_mfma_f32_16x16x32_f16(af[mi], bf[ni], acc[mi][ni], 0, 0, 0);
}

// C[m,n] = sum_k A[m,k]*Bt[n,k]; 2x(128x32) staged per barrier -> 32 MFMA/barrier
__device__ __forceinline__ void gemm_core(
    const f16* __restrict__ A, const f16* __restrict__ Bt,
    int lda, int ldb, int kOuter,
    f16* __restrict__ Ash, f16* __restrict__ Bsh,   // each [2][128*32]
    f32x4 acc[4][4], const Frag& fr)
{
  Stager sa, sb;
  sa.init(A, lda, fr);
  sb.init(Bt, ldb, fr);
  for (int kt = 0; kt < kOuter; ++kt) {
    const int ko = kt * 64;
    sa.stage(ko, Ash);       sa.stage(ko + 32, Ash + 128 * 32);
    sb.stage(ko, Bsh);       sb.stage(ko + 32, Bsh + 128 * 32);
    __syncthreads();
    mfma_round(Ash, Bsh, acc, fr);
    mfma_round(Ash + 128 * 32, Bsh + 128 * 32, acc, fr);
    __syncthreads();
  }
}

// ---------------- single cast launch: X (2M f4) then Wq/Wk/Wv (256K f4 each) ----------------
__global__ __launch_bounds__(256) void cast_all_kernel(
    const float* __restrict__ xs,
    const float* __restrict__ w0, const float* __restrict__ w1, const float* __restrict__ w2,
    f16* __restrict__ Xh, f16* __restrict__ o0, f16* __restrict__ o1, f16* __restrict__ o2)
{
  const int i = blockIdx.x * 256 + threadIdx.x;   // f4 index < 2883584 (exact grid)
  const float* src; f16* dst; int idx;
  if (i < 2097152) {
    src = xs; dst = Xh; idx = i;
  } else {
    const int j = i - 2097152;
    const int w = j >> 18;          // 262144 f4 per weight matrix
    idx = j & 262143;
    src = (w == 0) ? w0 : (w == 1) ? w1 : w2;
    dst = (w == 0) ? o0 : (w == 1) ? o1 : o2;
  }
  const float4 f = ((const float4*)src)[idx];
  f16x4 h;
  h.x = (f16)f.x; h.y = (f16)f.y; h.z = (f16)f.z; h.w = (f16)f.w;
  ((f16x4*)dst)[idx] = h;
}

// ---------------- merged projections: blocks [0,512) = fused QK item, [512,1024) = V^T item ----------------
// QK: per item stage X-tile + Wq/Wk tiles (2x32 buffers), 64 MFMA/barrier -> Qh, Kh (+bias, f16)
// VT: Vt[e][s] = sum_h Wv[e,h] X[s,h] + bv[e]  (BT-GEMM, writes V transposed directly)
__global__ __launch_bounds__(256, 2) void proj_kernel(
    const f16* __restrict__ X,
    const f16* __restrict__ Wq, const f16* __restrict__ Wk, const f16* __restrict__ Wv,
    const float* __restrict__ bq, const float* __restrict__ bk, const float* __restrict__ bv,
    f16* __restrict__ Qh, f16* __restrict__ Kh, f16* __restrict__ Vt)
{
  __shared__ __align__(16) f16 smem[3][2][BM * 32];   // 48 KB
  Frag fr;
  const int t = blockIdx.x;
  if (t < 512) {
    const int row0 = (t & 63) * BM, col0 = (t >> 6) * BN;
    Stager sa, sw0, sw1;
    sa.init(X + (size_t)row0 * EE, EE, fr);
    sw0.init(Wq + (size_t)col0 * EE, EE, fr);
    sw1.init(Wk + (size_t)col0 * EE, EE, fr);

    f32x4 acc[2][4][4] = {};

    for (int kt = 0; kt < EE / 64; ++kt) {
      const int ko = kt * 64;
      sa.stage(ko, smem[0][0]);   sa.stage(ko + 32, smem[0][1]);
      sw0.stage(ko, smem[1][0]);  sw0.stage(ko + 32, smem[1][1]);
      sw1.stage(ko, smem[2][0]);  sw1.stage(ko + 32, smem[2][1]);
      __syncthreads();
#pragma unroll
      for (int h = 0; h < 2; ++h) {
        f16x8 af[4];
#pragma unroll
        for (int mi = 0; mi < 4; ++mi)
          af[mi] = *(const f16x8*)(smem[0][h] + (fr.wy * 64 + mi * 16 + fr.l16) * 32 + fr.quadx * 8);
#pragma unroll
        for (int z = 0; z < 2; ++z) {
          f16x8 bf[4];
#pragma unroll
          for (int ni = 0; ni < 4; ++ni)
            bf[ni] = *(const f16x8*)(smem[1 + z][h] + (fr.wx * 64 + ni * 16 + fr.l16) * 32 + fr.quadx * 8);
#pragma unroll
          for (int mi = 0; mi < 4; ++mi)
#pragma unroll
            for (int ni = 0; ni < 4; ++ni)
              acc[z][mi][ni] = __builtin_amdgcn_mfma_f32_16x16x32_f16(af[mi], bf[ni], acc[z][mi][ni], 0, 0, 0);
        }
      }
      __syncthreads();
    }

#pragma unroll
    for (int z = 0; z < 2; ++z) {
      const float* bias = (z == 0) ? bq : bk;
      f16* out = (z == 0) ? Qh : Kh;
#pragma unroll
      for (int ni = 0; ni < 4; ++ni) {
        const int c = col0 + fr.wx * 64 + ni * 16 + fr.l16;
        const float bv2 = bias[c];
#pragma unroll
        for (int mi = 0; mi < 4; ++mi) {
          const int r = row0 + fr.wy * 64 + mi * 16 + fr.quad * 4;
#pragma unroll
          for (int i = 0; i < 4; ++i)
            out[(size_t)(r + i) * EE + c] = (f16)(acc[z][mi][ni][i] + bv2);
        }
      }
    }
  } else {
    const int u = t - 512;
    const int row0 = (u & 7) * BM;        // e
    const int sg0 = (u >> 3) * BN;        // global s in [0, BB*SS)
    const int b = sg0 / SS, s0 = sg0 % SS;
    f32x4 acc[4][4] = {};
    gemm_core(Wv + (size_t)row0 * EE, X + (size_t)sg0 * EE, EE, EE, EE / 64,
              smem[0][0], smem[1][0], acc, fr);
    f16* out = Vt + (size_t)b * EE * SS;
#pragma unroll
    for (int ni = 0; ni < 4; ++ni) {
      const int c = s0 + fr.wx * 64 + ni * 16 + fr.l16;
#pragma unroll
      for (int mi = 0; mi < 4; ++mi) {
        const int r = row0 + fr.wy * 64 + mi * 16 + fr.quad * 4;
#pragma unroll
        for (int i = 0; i < 4; ++i)
          out[(size_t)(r + i) * SS + c] = (f16)(acc[mi][ni][i] + bv[r + i]);
      }
    }
  }
}

// ---------------- scores: Sc[q,k] = (Q[q,:] . K[k,:]) / 32, lower-tri tiles only ----------------
__global__ __launch_bounds__(256) void scores_kernel(
    const f16* __restrict__ Q, const f16* __restrict__ Kh, f16* __restrict__ Sc)
{
  __shared__ __align__(16) f16 Ash[2][BM * 32];
  __shared__ __align__(16) f16 Bsh[2][BN * 32];
  const int t = blockIdx.x, b = blockIdx.z;
  int qt = 0;
  while ((qt + 1) * (qt + 2) / 2 <= t) ++qt;
  const int kt = t - qt * (qt + 1) / 2;
  const f16* A  = Q  + (size_t)b * SS * EE + (size_t)qt * BM * EE;
  const f16* Bp = Kh + (size_t)b * SS * EE + (size_t)kt * BN * EE;
  f16* out = Sc + (size_t)b * SS * SS;
  Frag fr;
  f32x4 acc[4][4] = {};
  gemm_core(A, Bp, EE, EE, EE / 64, Ash[0], Bsh[0], acc, fr);
  const float scale = 0.03125f;   // 1/sqrt(1024)
#pragma unroll
  for (int ni = 0; ni < 4; ++ni) {
    const int c = kt * BN + fr.wx * 64 + ni * 16 + fr.l16;
#pragma unroll
    for (int mi = 0; mi < 4; ++mi) {
      const int r = qt * BM + fr.wy * 64 + mi * 16 + fr.quad * 4;
#pragma unroll
      for (int i = 0; i < 4; ++i)
        out[(size_t)(r + i) * SS + c] = (f16)(acc[mi][ni][i] * scale);
    }
  }
}

// ---------------- in-place causal softmax over row q (vectorized f16x8) ----------------
__global__ __launch_bounds__(256) void softmax_kernel(f16* __restrict__ Sc)
{
  const int q = blockIdx.x, b = blockIdx.y;
  f16* row = Sc + (size_t)b * SS * SS + (size_t)q * SS;
  const int n = q + 1;
  const int kend = ((q >> 7) + 1) << 7;   // PV reads K up to this 128-boundary
  const int tid = threadIdx.x;
  const int i0 = tid * 8;

  float v[8];
  if (i0 + 8 <= n) {
    const f16x8 h = *(const f16x8*)(row + i0);
#pragma unroll
    for (int j = 0; j < 8; ++j) v[j] = (float)h[j];
  } else {
#pragma unroll
    for (int j = 0; j < 8; ++j) {
      const int idx = i0 + j;
      v[j] = (idx < n) ? (float)row[idx] : -1e30f;
    }
  }

  float m = v[0];
#pragma unroll
  for (int j = 1; j < 8; ++j) m = fmaxf(m, v[j]);
  __shared__ float red[4];
#pragma unroll
  for (int off = 32; off > 0; off >>= 1) m = fmaxf(m, __shfl_down(m, off));
  if ((tid & 63) == 0) red[tid >> 6] = m;
  __syncthreads();
  m = fmaxf(fmaxf(red[0], red[1]), fmaxf(red[2], red[3]));

  float sum = 0.f;
#pragma unroll
  for (int j = 0; j < 8; ++j) {
    v[j] = (i0 + j < n) ? __expf(v[j] - m) : 0.f;
    sum += v[j];
  }
#pragma unroll
  for (int off = 32; off > 0; off >>= 1) sum += __shfl_down(sum, off);
  __syncthreads();
  if ((tid & 63) == 0) red[tid >> 6] = sum;
  __syncthreads();
  sum = red[0] + red[1] + red[2] + red[3];
  const float inv = 1.f / sum;

  if (i0 < kend) {
    f16x8 h;
#pragma unroll
    for (int j = 0; j < 8; ++j) h[j] = (f16)(v[j] * inv);   // v==0 beyond n
    *(f16x8*)(row + i0) = h;
  }
}

// ---------------- PV: Y[q,e] = sum_{k<=q} P[q,k] * Vt[e,k], fp32 out ----------------
// Flat 512-block grid with complementary-pair remap: block t and t+256 map to
// qt=15-qh and qt=qh (same et,b) -> uniform per-CU K-tile load.
__global__ __launch_bounds__(256) void pv_kernel(
    const f16* __restrict__ P, const f16* __restrict__ Vt, float* __restrict__ Y)
{
  __shared__ __align__(16) f16 Ash[2][BM * 32];
  __shared__ __align__(16) f16 Bsh[2][BN * 32];
  const int t = blockIdx.x;
  const int u = t & 255;
  const int qh = u & 7, et = (u >> 3) & 7, b = u >> 6;
  const int qt = (t < 256) ? (15 - qh) : qh;
  const f16* A  = P  + (size_t)b * SS * SS + (size_t)qt * BM * SS;
  const f16* Bp = Vt + (size_t)b * EE * SS + (size_t)et * BN * SS;
  float* out = Y + (size_t)b * SS * EE;
  Frag fr;
  f32x4 acc[4][4] = {};
  gemm_core(A, Bp, SS, SS, (qt + 1) * 2, Ash[0], Bsh[0], acc, fr);
#pragma unroll
  for (int ni = 0; ni < 4; ++ni) {
    const int c = et * BN + fr.wx * 64 + ni * 16 + fr.l16;
#pragma unroll
    for (int mi = 0; mi < 4; ++mi) {
      const int r = qt * BM + fr.wy * 64 + mi * 16 + fr.quad * 4;
#pragma unroll
      for (int i = 0; i < 4; ++i)
        out[(size_t)(r + i) * EE + c] = acc[mi][ni][i];
    }
  }
}

extern "C" void kernel_launch(void* const* d_in, const int* in_sizes, int n_in,
                              void* d_out, int out_size, void* d_ws, size_t ws_size,
                              hipStream_t stream)
{
  const float* xs  = (const float*)d_in[0];
  const float* WQw = (const float*)d_in[1];
  const float* WQb = (const float*)d_in[2];
  const float* WKw = (const float*)d_in[3];
  const float* WKb = (const float*)d_in[4];
  const float* WVw = (const float*)d_in[5];
  const float* WVb = (const float*)d_in[6];

  const size_t ME = (size_t)BB * SS * EE;   // 8M tokens*dim
  const size_t WE = (size_t)EE * EE;        // 1M weight elems

  f16* Xh = (f16*)d_ws;
  f16* Wq = Xh + ME;
  f16* Wk = Wq + WE;
  f16* Wv = Wk + WE;
  f16* Qh = Wv + WE;
  f16* Kh = Qh + ME;
  f16* Vt = Kh + ME;
  f16* Sc = Vt + ME;   // BB*SS*SS f16 = 32 MiB

  // 1) casts (one launch): (8M + 3*1M)/4 = 2883584 f4 -> 11264 blocks exact
  cast_all_kernel<<<dim3(11264), 256, 0, stream>>>(
      xs, WQw, WKw, WVw, Xh, Wq, Wk, Wv);

  // 2) projections (one launch): 512 QK items + 512 VT items
  proj_kernel<<<dim3(1024), 256, 0, stream>>>(
      Xh, Wq, Wk, Wv, WQb, WKb, WVb, Qh, Kh, Vt);

  // 3) scores (lower-tri tiles)
  const int nTri = (SS / BM) * (SS / BM + 1) / 2;   // 136
  scores_kernel<<<dim3(nTri, 1, BB), 256, 0, stream>>>(Qh, Kh, Sc);

  // 4) softmax
  softmax_kernel<<<dim3(SS, BB), 256, 0, stream>>>(Sc);

  // 5) PV
  pv_kernel<<<dim3(512), 256, 0, stream>>>(Sc, Vt, (float*)d_out);
}